// Round 3
// baseline (602.245 us; speedup 1.0000x reference)
//
#include <hip/hip_runtime.h>

#define BINS 2048

// ---- monotonic float<->uint ordering for atomic min/max on floats ----
__device__ __forceinline__ unsigned ordf(float f) {
    unsigned u = __float_as_uint(f);
    return (u & 0x80000000u) ? ~u : (u | 0x80000000u);
}
__device__ __forceinline__ float unordf(unsigned u) {
    return __uint_as_float((u & 0x80000000u) ? (u ^ 0x80000000u) : ~u);
}

// ws layout (as unsigned*):
//   ws[0] = ordered min (atomicMin), ws[1] = ordered max (atomicMax)
//   ws[2 .. 2+BINS) = histogram counts (unsigned)

__global__ void init_ws(unsigned* __restrict__ ws) {
    int i = blockIdx.x * blockDim.x + threadIdx.x;
    if (i < 2 + BINS) ws[i] = (i == 0) ? 0xFFFFFFFFu : 0u;
}

__global__ void minmax_kernel(const float4* __restrict__ xv, int nvec,
                              const float* __restrict__ x, int n,
                              unsigned* __restrict__ ws) {
    float mn = INFINITY, mx = -INFINITY;
    int stride = gridDim.x * blockDim.x;
    for (int i = blockIdx.x * blockDim.x + threadIdx.x; i < nvec; i += stride) {
        float4 v = xv[i];
        mn = fminf(mn, fminf(fminf(v.x, v.y), fminf(v.z, v.w)));
        mx = fmaxf(mx, fmaxf(fmaxf(v.x, v.y), fmaxf(v.z, v.w)));
    }
    if (blockIdx.x == 0 && threadIdx.x == 0) {  // tail (none for this size)
        for (int j = nvec * 4; j < n; ++j) {
            float v = x[j];
            mn = fminf(mn, v);
            mx = fmaxf(mx, v);
        }
    }
    #pragma unroll
    for (int off = 32; off > 0; off >>= 1) {
        mn = fminf(mn, __shfl_xor(mn, off));
        mx = fmaxf(mx, __shfl_xor(mx, off));
    }
    if ((threadIdx.x & 63) == 0) {
        atomicMin(&ws[0], ordf(mn));
        atomicMax(&ws[1], ordf(mx));
    }
}

// Bin exactly like a float64 numpy _histc:
//   pos = (double(v) - mn) / rng;  idx = int32(pos * 2048);  clip
__device__ __forceinline__ int histc_bin_f64(float v, double mn, double rng, bool pos_rng) {
    double pos = pos_rng ? (((double)v - mn) / rng) : 0.0;
    int idx = (int)(pos * (double)BINS);   // trunc toward zero == astype(int32)
    return min(max(idx, 0), BINS - 1);
}

__global__ void __launch_bounds__(512) hist_kernel(const float4* __restrict__ xv, int nvec,
                                                   const float* __restrict__ x, int n,
                                                   unsigned* __restrict__ ws) {
    __shared__ unsigned lh[BINS];
    for (int b = threadIdx.x; b < BINS; b += blockDim.x) lh[b] = 0u;
    __syncthreads();

    double mn = (double)unordf(ws[0]);
    double mx = (double)unordf(ws[1]);
    double rng = mx - mn;                 // exact in f64 (both operands are f32)
    bool pos_rng = (rng > 0.0);

    int stride = gridDim.x * blockDim.x;
    for (int i = blockIdx.x * blockDim.x + threadIdx.x; i < nvec; i += stride) {
        float4 v = xv[i];
        atomicAdd(&lh[histc_bin_f64(v.x, mn, rng, pos_rng)], 1u);
        atomicAdd(&lh[histc_bin_f64(v.y, mn, rng, pos_rng)], 1u);
        atomicAdd(&lh[histc_bin_f64(v.z, mn, rng, pos_rng)], 1u);
        atomicAdd(&lh[histc_bin_f64(v.w, mn, rng, pos_rng)], 1u);
    }
    if (blockIdx.x == 0 && threadIdx.x == 0) {  // tail (none for this size)
        for (int j = nvec * 4; j < n; ++j)
            atomicAdd(&lh[histc_bin_f64(x[j], mn, rng, pos_rng)], 1u);
    }
    __syncthreads();
    for (int b = threadIdx.x; b < BINS; b += blockDim.x) {
        unsigned c = lh[b];
        if (c) atomicAdd(&ws[2 + b], c);
    }
}

// Replicates _combine in float64 (matching a numpy-f64 gold reference).
// In f64 the new-hist source (src_w == dst_w, src_min == dst_min) maps EXACTLY
// bin i -> bin i: (smax-smin) is exact, /2048 is an exponent shift, src_w*i fits
// in 35 bits, and the quotient divides out exactly. No last-ulp coin flips.
__global__ void combine_kernel(const float* __restrict__ prev_hist,
                               const float* __restrict__ prev_min,
                               const float* __restrict__ prev_max,
                               const unsigned* __restrict__ ws,
                               float* __restrict__ out) {
    __shared__ float acc[BINS];
    for (int b = threadIdx.x; b < BINS; b += blockDim.x) acc[b] = 0.0f;
    __syncthreads();

    float nmn_f = unordf(ws[0]);
    float nmx_f = unordf(ws[1]);
    float pmn_f = prev_min[0];
    float pmx_f = prev_max[0];
    float cmin_f = fminf(nmn_f, pmn_f);
    float cmax_f = fmaxf(nmx_f, pmx_f);

    double cmin = (double)cmin_f;
    double cmax = (double)cmax_f;
    double dst_w = (cmax - cmin) / (double)BINS;
    double safe_dw = (dst_w != 0.0) ? dst_w : 1.0;
    bool dw_nz = (dst_w != 0.0);

    for (int s = 0; s < 2; ++s) {
        double smin = s ? (double)nmn_f : (double)pmn_f;
        double smax = s ? (double)nmx_f : (double)pmx_f;
        double src_w = (smax - smin) / (double)BINS;
        bool degenerate = (src_w == 0.0) || !dw_nz;
        double safe_sw = (src_w != 0.0) ? src_w : 1.0;

        for (int i = threadIdx.x; i < BINS; i += blockDim.x) {
            double cnt = s ? (double)ws[2 + i] : (double)prev_hist[i];
            double begin = smin + src_w * (double)i;
            double end   = begin + src_w;
            double db  = dw_nz ? floor((begin - cmin) / safe_dw) : 0.0;
            double db2 = dw_nz
                           ? fmin(floor((end - cmin) / safe_dw), (double)(BINS - 1))
                           : 0.0;
            double dst_bin_end = cmin + dst_w * (db + 1.0);
            double frac = rint((dst_bin_end - begin) / safe_sw * cnt);  // RNE == np.round
            double c1 = degenerate ? cnt : fmin(frac, cnt);
            double c2 = cnt - c1;
            int ib  = min(max((int)db, 0), BINS - 1);
            int ib2 = min(max((int)db2, 0), BINS - 1);
            // c1/c2 are integer-valued and per-bin sums < 2^24 -> f32 adds exact
            atomicAdd(&acc[ib], (float)c1);
            atomicAdd(&acc[ib2], (float)c2);
        }
    }
    __syncthreads();
    for (int b = threadIdx.x; b < BINS; b += blockDim.x) out[b] = acc[b];
    if (threadIdx.x == 0) {
        out[BINS] = cmin_f;
        out[BINS + 1] = cmax_f;
    }
}

extern "C" void kernel_launch(void* const* d_in, const int* in_sizes, int n_in,
                              void* d_out, int out_size, void* d_ws, size_t ws_size,
                              hipStream_t stream) {
    const float* x         = (const float*)d_in[0];
    const float* prev_hist = (const float*)d_in[1];
    const float* prev_min  = (const float*)d_in[2];
    const float* prev_max  = (const float*)d_in[3];
    float* out   = (float*)d_out;
    unsigned* ws = (unsigned*)d_ws;

    int n = in_sizes[0];
    int nvec = n >> 2;

    init_ws<<<(2 + BINS + 255) / 256, 256, 0, stream>>>(ws);
    minmax_kernel<<<2048, 256, 0, stream>>>((const float4*)x, nvec, x, n, ws);
    hist_kernel<<<512, 512, 0, stream>>>((const float4*)x, nvec, x, n, ws);
    combine_kernel<<<1, 256, 0, stream>>>(prev_hist, prev_min, prev_max, ws, out);
}

// Round 4
// 429.763 us; speedup vs baseline: 1.4013x; 1.4013x over previous
//
#include <hip/hip_runtime.h>

#define BINS 2048
#define MM_BLOCKS 2048
#define MM_THREADS 256
#define H_BLOCKS 512
#define H_THREADS 512

// ws word layout:
//   [0] = final min (f32), [1] = final max (f32)
//   [2 .. 2+BINS)                        = histogram bins (u32, global atomicAdd)
//   [2+BINS .. 2+BINS+2*MM_BLOCKS)       = per-block (min,max) partial pairs (f32)
#define WS_PAIRS (2 + BINS)
#define WS_WORDS (2 + BINS + 2 * MM_BLOCKS)

__global__ void zero_ws(unsigned* __restrict__ ws) {
    int i = blockIdx.x * blockDim.x + threadIdx.x;
    if (i < WS_WORDS) ws[i] = 0u;
}

// Pass 1a: per-block min/max partials. 4-way unrolled independent loads (4 KB
// in flight per wave) — no global atomics at all.
__global__ void __launch_bounds__(MM_THREADS) minmax_partial(
        const float4* __restrict__ xv, int nvec,
        const float* __restrict__ x, int n,
        float* __restrict__ wsf) {
    float mn0 = INFINITY, mn1 = INFINITY, mn2 = INFINITY, mn3 = INFINITY;
    float mx0 = -INFINITY, mx1 = -INFINITY, mx2 = -INFINITY, mx3 = -INFINITY;
    const int s = gridDim.x * blockDim.x;
    int i = blockIdx.x * blockDim.x + threadIdx.x;
    for (; i + 3 * s < nvec; i += 4 * s) {
        float4 a = xv[i];
        float4 b = xv[i + s];
        float4 c = xv[i + 2 * s];
        float4 d = xv[i + 3 * s];
        mn0 = fminf(mn0, fminf(fminf(a.x, a.y), fminf(a.z, a.w)));
        mx0 = fmaxf(mx0, fmaxf(fmaxf(a.x, a.y), fmaxf(a.z, a.w)));
        mn1 = fminf(mn1, fminf(fminf(b.x, b.y), fminf(b.z, b.w)));
        mx1 = fmaxf(mx1, fmaxf(fmaxf(b.x, b.y), fmaxf(b.z, b.w)));
        mn2 = fminf(mn2, fminf(fminf(c.x, c.y), fminf(c.z, c.w)));
        mx2 = fmaxf(mx2, fmaxf(fmaxf(c.x, c.y), fmaxf(c.z, c.w)));
        mn3 = fminf(mn3, fminf(fminf(d.x, d.y), fminf(d.z, d.w)));
        mx3 = fmaxf(mx3, fmaxf(fmaxf(d.x, d.y), fmaxf(d.z, d.w)));
    }
    for (; i < nvec; i += s) {
        float4 a = xv[i];
        mn0 = fminf(mn0, fminf(fminf(a.x, a.y), fminf(a.z, a.w)));
        mx0 = fmaxf(mx0, fmaxf(fmaxf(a.x, a.y), fmaxf(a.z, a.w)));
    }
    if (blockIdx.x == 0 && threadIdx.x == 0) {  // scalar tail (n%4, zero here)
        for (int j = nvec * 4; j < n; ++j) {
            float v = x[j];
            mn0 = fminf(mn0, v);
            mx0 = fmaxf(mx0, v);
        }
    }
    float mn = fminf(fminf(mn0, mn1), fminf(mn2, mn3));
    float mx = fmaxf(fmaxf(mx0, mx1), fmaxf(mx2, mx3));
    #pragma unroll
    for (int off = 32; off > 0; off >>= 1) {
        mn = fminf(mn, __shfl_xor(mn, off));
        mx = fmaxf(mx, __shfl_xor(mx, off));
    }
    __shared__ float smn[MM_THREADS / 64], smx[MM_THREADS / 64];
    if ((threadIdx.x & 63) == 0) {
        smn[threadIdx.x >> 6] = mn;
        smx[threadIdx.x >> 6] = mx;
    }
    __syncthreads();
    if (threadIdx.x == 0) {
        #pragma unroll
        for (int w = 1; w < MM_THREADS / 64; ++w) {
            mn = fminf(mn, smn[w]);
            mx = fmaxf(mx, smx[w]);
        }
        wsf[WS_PAIRS + 2 * blockIdx.x] = mn;
        wsf[WS_PAIRS + 2 * blockIdx.x + 1] = mx;
    }
}

// Pass 1b: reduce the MM_BLOCKS partial pairs -> wsf[0], wsf[1]. One tiny block.
__global__ void minmax_final(float* __restrict__ wsf) {
    float mn = INFINITY, mx = -INFINITY;
    for (int p = threadIdx.x; p < MM_BLOCKS; p += blockDim.x) {
        mn = fminf(mn, wsf[WS_PAIRS + 2 * p]);
        mx = fmaxf(mx, wsf[WS_PAIRS + 2 * p + 1]);
    }
    #pragma unroll
    for (int off = 32; off > 0; off >>= 1) {
        mn = fminf(mn, __shfl_xor(mn, off));
        mx = fmaxf(mx, __shfl_xor(mx, off));
    }
    __shared__ float smn[4], smx[4];
    if ((threadIdx.x & 63) == 0) {
        smn[threadIdx.x >> 6] = mn;
        smx[threadIdx.x >> 6] = mx;
    }
    __syncthreads();
    if (threadIdx.x == 0) {
        #pragma unroll
        for (int w = 1; w < 4; ++w) {
            mn = fminf(mn, smn[w]);
            mx = fmaxf(mx, smx[w]);
        }
        wsf[0] = mn;
        wsf[1] = mx;
    }
}

// f64 binning via hoisted reciprocal: idx = int((v-mn) * (2048/rng)).
// 2048/rng folds the exact *2048 (power of 2) into one f64 mul; differs from the
// reference's ((v-mn)/rng)*2048 only when the product sits within ~1ulp(f64) of
// an integer — probability ~2^-51 per element, i.e. never at n=67M.
__device__ __forceinline__ int histc_bin(float v, double mn, double sc) {
    int idx = (int)(((double)v - mn) * sc);   // trunc toward zero == astype(int32)
    return min(max(idx, 0), BINS - 1);
}

__global__ void __launch_bounds__(H_THREADS) hist_kernel(
        const float4* __restrict__ xv, int nvec,
        const float* __restrict__ x, int n,
        unsigned* __restrict__ ws, const float* __restrict__ wsf) {
    __shared__ unsigned lh[BINS];
    for (int b = threadIdx.x; b < BINS; b += blockDim.x) lh[b] = 0u;
    __syncthreads();

    double mn = (double)wsf[0];
    double rng = (double)wsf[1] - mn;             // exact in f64 (f32 operands)
    double sc = (rng > 0.0) ? ((double)BINS / rng) : 0.0;

    const int s = gridDim.x * blockDim.x;
    int i = blockIdx.x * blockDim.x + threadIdx.x;
    for (; i + 3 * s < nvec; i += 4 * s) {
        float4 a = xv[i];
        float4 b = xv[i + s];
        float4 c = xv[i + 2 * s];
        float4 d = xv[i + 3 * s];
        atomicAdd(&lh[histc_bin(a.x, mn, sc)], 1u);
        atomicAdd(&lh[histc_bin(a.y, mn, sc)], 1u);
        atomicAdd(&lh[histc_bin(a.z, mn, sc)], 1u);
        atomicAdd(&lh[histc_bin(a.w, mn, sc)], 1u);
        atomicAdd(&lh[histc_bin(b.x, mn, sc)], 1u);
        atomicAdd(&lh[histc_bin(b.y, mn, sc)], 1u);
        atomicAdd(&lh[histc_bin(b.z, mn, sc)], 1u);
        atomicAdd(&lh[histc_bin(b.w, mn, sc)], 1u);
        atomicAdd(&lh[histc_bin(c.x, mn, sc)], 1u);
        atomicAdd(&lh[histc_bin(c.y, mn, sc)], 1u);
        atomicAdd(&lh[histc_bin(c.z, mn, sc)], 1u);
        atomicAdd(&lh[histc_bin(c.w, mn, sc)], 1u);
        atomicAdd(&lh[histc_bin(d.x, mn, sc)], 1u);
        atomicAdd(&lh[histc_bin(d.y, mn, sc)], 1u);
        atomicAdd(&lh[histc_bin(d.z, mn, sc)], 1u);
        atomicAdd(&lh[histc_bin(d.w, mn, sc)], 1u);
    }
    for (; i < nvec; i += s) {
        float4 a = xv[i];
        atomicAdd(&lh[histc_bin(a.x, mn, sc)], 1u);
        atomicAdd(&lh[histc_bin(a.y, mn, sc)], 1u);
        atomicAdd(&lh[histc_bin(a.z, mn, sc)], 1u);
        atomicAdd(&lh[histc_bin(a.w, mn, sc)], 1u);
    }
    if (blockIdx.x == 0 && threadIdx.x == 0) {  // scalar tail (zero here)
        for (int j = nvec * 4; j < n; ++j)
            atomicAdd(&lh[histc_bin(x[j], mn, sc)], 1u);
    }
    __syncthreads();
    for (int b = threadIdx.x; b < BINS; b += blockDim.x) {
        unsigned c = lh[b];
        if (c) atomicAdd(&ws[2 + b], c);
    }
}

// Unchanged from round 3 (passing): _combine replicated in float64.
__global__ void combine_kernel(const float* __restrict__ prev_hist,
                               const float* __restrict__ prev_min,
                               const float* __restrict__ prev_max,
                               const unsigned* __restrict__ ws,
                               const float* __restrict__ wsf,
                               float* __restrict__ out) {
    __shared__ float acc[BINS];
    for (int b = threadIdx.x; b < BINS; b += blockDim.x) acc[b] = 0.0f;
    __syncthreads();

    float nmn_f = wsf[0];
    float nmx_f = wsf[1];
    float pmn_f = prev_min[0];
    float pmx_f = prev_max[0];
    float cmin_f = fminf(nmn_f, pmn_f);
    float cmax_f = fmaxf(nmx_f, pmx_f);

    double cmin = (double)cmin_f;
    double cmax = (double)cmax_f;
    double dst_w = (cmax - cmin) / (double)BINS;
    double safe_dw = (dst_w != 0.0) ? dst_w : 1.0;
    bool dw_nz = (dst_w != 0.0);

    for (int s = 0; s < 2; ++s) {
        double smin = s ? (double)nmn_f : (double)pmn_f;
        double smax = s ? (double)nmx_f : (double)pmx_f;
        double src_w = (smax - smin) / (double)BINS;
        bool degenerate = (src_w == 0.0) || !dw_nz;
        double safe_sw = (src_w != 0.0) ? src_w : 1.0;

        for (int i = threadIdx.x; i < BINS; i += blockDim.x) {
            double cnt = s ? (double)ws[2 + i] : (double)prev_hist[i];
            double begin = smin + src_w * (double)i;
            double end   = begin + src_w;
            double db  = dw_nz ? floor((begin - cmin) / safe_dw) : 0.0;
            double db2 = dw_nz
                           ? fmin(floor((end - cmin) / safe_dw), (double)(BINS - 1))
                           : 0.0;
            double dst_bin_end = cmin + dst_w * (db + 1.0);
            double frac = rint((dst_bin_end - begin) / safe_sw * cnt);  // RNE == np.round
            double c1 = degenerate ? cnt : fmin(frac, cnt);
            double c2 = cnt - c1;
            int ib  = min(max((int)db, 0), BINS - 1);
            int ib2 = min(max((int)db2, 0), BINS - 1);
            atomicAdd(&acc[ib], (float)c1);   // integer-valued, < 2^24 -> exact
            atomicAdd(&acc[ib2], (float)c2);
        }
    }
    __syncthreads();
    for (int b = threadIdx.x; b < BINS; b += blockDim.x) out[b] = acc[b];
    if (threadIdx.x == 0) {
        out[BINS] = cmin_f;
        out[BINS + 1] = cmax_f;
    }
}

extern "C" void kernel_launch(void* const* d_in, const int* in_sizes, int n_in,
                              void* d_out, int out_size, void* d_ws, size_t ws_size,
                              hipStream_t stream) {
    const float* x         = (const float*)d_in[0];
    const float* prev_hist = (const float*)d_in[1];
    const float* prev_min  = (const float*)d_in[2];
    const float* prev_max  = (const float*)d_in[3];
    float* out   = (float*)d_out;
    unsigned* ws = (unsigned*)d_ws;
    float* wsf   = (float*)d_ws;

    int n = in_sizes[0];
    int nvec = n >> 2;

    zero_ws<<<(WS_WORDS + 255) / 256, 256, 0, stream>>>(ws);
    minmax_partial<<<MM_BLOCKS, MM_THREADS, 0, stream>>>((const float4*)x, nvec, x, n, wsf);
    minmax_final<<<1, 256, 0, stream>>>(wsf);
    hist_kernel<<<H_BLOCKS, H_THREADS, 0, stream>>>((const float4*)x, nvec, x, n, ws, wsf);
    combine_kernel<<<1, 256, 0, stream>>>(prev_hist, prev_min, prev_max, ws, wsf, out);
}